// Round 1
// baseline (193.162 us; speedup 1.0000x reference)
//
#include <hip/hip_runtime.h>

#define N_NODES 50000
#define N_EDGES 800000
// D_FEAT=64, D_EDGE=16, D_HID=16, D_MSG=64, D_OUT=64

__device__ __forceinline__ unsigned fkey(float f) {
    unsigned u = __float_as_uint(f);
    return (u & 0x80000000u) ? ~u : (u | 0x80000000u);
}
// key(-inf) = ~0xFF800000 = 0x007FFFFF
#define KEY_NEG_INF 0x007FFFFFu

// ---------------- init: fill rkey with key(-inf) ----------------
__global__ __launch_bounds__(256) void init_kernel(unsigned* __restrict__ rkey) {
    // 50000*64 = 3,200,000 u32 = 800,000 uint4 ; grid = 3125*256 exact
    const int i = blockIdx.x * 256 + threadIdx.x;
    reinterpret_cast<uint4*>(rkey)[i] =
        make_uint4(KEY_NEG_INF, KEY_NEG_INF, KEY_NEG_INF, KEY_NEG_INF);
}

// ---------------- edge kernel: msg MLP + atomic max ----------------
__global__ __launch_bounds__(256) void edge_kernel(
    const float* __restrict__ x, const float* __restrict__ ef,
    const int* __restrict__ src, const int* __restrict__ dst,
    const float* __restrict__ W1, const float* __restrict__ b1,
    const float* __restrict__ W2, const float* __restrict__ b2,
    unsigned* __restrict__ rkey)
{
    const int e    = blockIdx.x * 256 + threadIdx.x;  // grid = 3125*256 = 800000 exact
    const int lane = threadIdx.x & 63;
    const int w    = threadIdx.x >> 6;

    __shared__ float mld[4][64][17];
    __shared__ int   dld[4][64];

    // ---- load inputs: [edge_feats(16), x[src](64)] ----
    float in[80];
    const float4* efp = reinterpret_cast<const float4*>(ef) + (size_t)e * 4;
#pragma unroll
    for (int c = 0; c < 4; ++c) {
        float4 t = efp[c];
        in[4*c+0]=t.x; in[4*c+1]=t.y; in[4*c+2]=t.z; in[4*c+3]=t.w;
    }
    const int s = src[e];
    const int d = dst[e];
    dld[w][lane] = d;
    const float4* xp = reinterpret_cast<const float4*>(x) + (size_t)s * 16;
#pragma unroll
    for (int c = 0; c < 16; ++c) {
        float4 t = xp[c];
        in[16+4*c+0]=t.x; in[16+4*c+1]=t.y; in[16+4*c+2]=t.z; in[16+4*c+3]=t.w;
    }

    // ---- hidden: h = relu(in @ W1 + b1), W1[80][16] (uniform -> s_load) ----
    float h[16];
#pragma unroll
    for (int k = 0; k < 16; ++k) h[k] = b1[k];
#pragma unroll
    for (int i = 0; i < 80; ++i)
#pragma unroll
        for (int k = 0; k < 16; ++k)
            h[k] = fmaf(in[i], W1[i*16 + k], h[k]);
#pragma unroll
    for (int k = 0; k < 16; ++k) h[k] = fmaxf(h[k], 0.0f);

    const int er = lane >> 4;   // 0..3
    const int jj = lane & 15;   // 0..15

    // ---- output in chunks of 16 feats: m = h @ W2 + b2, W2[16][64] ----
#pragma unroll
    for (int j0 = 0; j0 < 64; j0 += 16) {
        float m[16];
#pragma unroll
        for (int t = 0; t < 16; ++t) m[t] = b2[j0 + t];
#pragma unroll
        for (int k = 0; k < 16; ++k)
#pragma unroll
            for (int t = 0; t < 16; ++t)
                m[t] = fmaf(h[k], W2[k*64 + j0 + t], m[t]);

        __syncthreads();  // previous chunk's reads done
#pragma unroll
        for (int t = 0; t < 16; ++t) mld[w][lane][t] = m[t];
        __syncthreads();  // writes visible

        // coalesced atomics: 16 lanes cover 16 consecutive feats of one dst row
#pragma unroll
        for (int eg = 0; eg < 16; ++eg) {
            const int ee = (eg << 2) | er;
            const float mv = mld[w][ee][jj];
            const int dd = dld[w][ee];
            atomicMax(&rkey[((size_t)dd << 6) + (unsigned)(j0 + jj)], fkey(mv));
        }
    }
}

// ---------------- node kernel: decode + update MLP ----------------
// NOTE: rkey and out alias (both d_out). No __restrict__ on them; all reads
// of this thread's row happen before its writes in program order.
__global__ __launch_bounds__(256) void node_kernel(
    const float* __restrict__ x, const unsigned* rkey,
    const float* __restrict__ W1, const float* __restrict__ b1,
    const float* __restrict__ W2, const float* __restrict__ b2,
    float* out)
{
    const int v = blockIdx.x * 256 + threadIdx.x;
    if (v >= N_NODES) return;

    float in[128];
    const float4* xp = reinterpret_cast<const float4*>(x) + (size_t)v * 16;
#pragma unroll
    for (int c = 0; c < 16; ++c) {
        float4 t = xp[c];
        in[4*c+0]=t.x; in[4*c+1]=t.y; in[4*c+2]=t.z; in[4*c+3]=t.w;
    }
    const uint4* rp = reinterpret_cast<const uint4*>(rkey) + (size_t)v * 16;
#pragma unroll
    for (int c = 0; c < 16; ++c) {
        uint4 t = rp[c];
        unsigned ks[4] = {t.x, t.y, t.z, t.w};
#pragma unroll
        for (int q = 0; q < 4; ++q) {
            unsigned k = ks[q];
            unsigned u = (k & 0x80000000u) ? (k ^ 0x80000000u) : ~k;
            float f = __uint_as_float(u);
            // -inf (no in-edges) or non-finite -> 0, matching jnp.where(isfinite)
            if (!(f >= -3.402823466e38f && f <= 3.402823466e38f)) f = 0.0f;
            in[64 + 4*c + q] = f;
        }
    }

    float h[16];
#pragma unroll
    for (int k = 0; k < 16; ++k) h[k] = b1[k];
#pragma unroll
    for (int i = 0; i < 128; ++i)
#pragma unroll
        for (int k = 0; k < 16; ++k)
            h[k] = fmaf(in[i], W1[i*16 + k], h[k]);
#pragma unroll
    for (int k = 0; k < 16; ++k) h[k] = fmaxf(h[k], 0.0f);

    float* op = out + (size_t)v * 64;
#pragma unroll
    for (int c = 0; c < 16; ++c) {
        float oo[4];
#pragma unroll
        for (int q = 0; q < 4; ++q) {
            float a = b2[4*c + q];
#pragma unroll
            for (int k = 0; k < 16; ++k)
                a = fmaf(h[k], W2[k*64 + 4*c + q], a);
            oo[q] = a;
        }
        float4 o; o.x=oo[0]; o.y=oo[1]; o.z=oo[2]; o.w=oo[3];
        reinterpret_cast<float4*>(op)[c] = o;
    }
}

extern "C" void kernel_launch(void* const* d_in, const int* in_sizes, int n_in,
                              void* d_out, int out_size, void* d_ws, size_t ws_size,
                              hipStream_t stream) {
    const float* x   = (const float*)d_in[0];
    const float* ef  = (const float*)d_in[1];
    const int*   src = (const int*)d_in[2];
    const int*   dst = (const int*)d_in[3];
    const float* mW1 = (const float*)d_in[4];
    const float* mb1 = (const float*)d_in[5];
    const float* mW2 = (const float*)d_in[6];
    const float* mb2 = (const float*)d_in[7];
    const float* uW1 = (const float*)d_in[8];
    const float* ub1 = (const float*)d_in[9];
    const float* uW2 = (const float*)d_in[10];
    const float* ub2 = (const float*)d_in[11];

    unsigned* rkey = (unsigned*)d_out;  // 50000*64 u32 = 12.8 MB, reuse d_out
    float*    out  = (float*)d_out;

    hipLaunchKernelGGL(init_kernel, dim3(3125), dim3(256), 0, stream, rkey);
    hipLaunchKernelGGL(edge_kernel, dim3(3125), dim3(256), 0, stream,
                       x, ef, src, dst, mW1, mb1, mW2, mb2, rkey);
    hipLaunchKernelGGL(node_kernel, dim3((N_NODES + 255) / 256), dim3(256), 0, stream,
                       x, rkey, uW1, ub1, uW2, ub2, out);
}

// Round 2
// 192.226 us; speedup vs baseline: 1.0049x; 1.0049x over previous
//
#include <hip/hip_runtime.h>

#define N_NODES 50000
#define N_EDGES 800000
// D_FEAT=64, D_EDGE=16, D_HID=16, D_MSG=64, D_OUT=64

__device__ __forceinline__ unsigned fkey(float f) {
    unsigned u = __float_as_uint(f);
    return (u & 0x80000000u) ? ~u : (u | 0x80000000u);
}
// key(-inf) = ~0xFF800000 = 0x007FFFFF
#define KEY_NEG_INF 0x007FFFFFu

// wave-local LDS fence: single-wave block, no s_barrier needed (DS pipe is
// in-order per wave); asm waitcnt + sched_barrier per guide rule 18.
__device__ __forceinline__ void wave_lds_fence() {
    asm volatile("s_waitcnt lgkmcnt(0)" ::: "memory");
    __builtin_amdgcn_sched_barrier(0);
}

// ---------------- init: fill rkey with key(-inf) ----------------
__global__ __launch_bounds__(256) void init_kernel(unsigned* __restrict__ rkey) {
    // 50000*64 = 3,200,000 u32 = 800,000 uint4 ; grid = 3125*256 exact
    const int i = blockIdx.x * 256 + threadIdx.x;
    reinterpret_cast<uint4*>(rkey)[i] =
        make_uint4(KEY_NEG_INF, KEY_NEG_INF, KEY_NEG_INF, KEY_NEG_INF);
}

// ---------------- edge kernel: msg MLP + atomic max ----------------
// ONE WAVE per block: no __syncthreads -> atomics are never vmcnt-drained
// inside the kernel (the old 4x barrier drain was the 156us stall).
__global__ __launch_bounds__(64) void edge_kernel(
    const float* __restrict__ x, const float* __restrict__ ef,
    const int* __restrict__ src, const int* __restrict__ dst,
    const float* __restrict__ W1, const float* __restrict__ b1,
    const float* __restrict__ W2, const float* __restrict__ b2,
    unsigned* __restrict__ rkey)
{
    const int lane = threadIdx.x;                 // 0..63
    const int e    = blockIdx.x * 64 + lane;      // grid = 12500*64 = 800000 exact

    __shared__ unsigned mld[64][17];  // stride 17: conflict-free b32 writes
    __shared__ int      dld[64];

    // ---- load inputs: [edge_feats(16), x[src](64)] ----
    float in[80];
    const float4* efp = reinterpret_cast<const float4*>(ef) + (size_t)e * 4;
#pragma unroll
    for (int c = 0; c < 4; ++c) {
        float4 t = efp[c];
        in[4*c+0]=t.x; in[4*c+1]=t.y; in[4*c+2]=t.z; in[4*c+3]=t.w;
    }
    const int s = src[e];
    dld[lane] = dst[e];
    const float4* xp = reinterpret_cast<const float4*>(x) + (size_t)s * 16;
#pragma unroll
    for (int c = 0; c < 16; ++c) {
        float4 t = xp[c];
        in[16+4*c+0]=t.x; in[16+4*c+1]=t.y; in[16+4*c+2]=t.z; in[16+4*c+3]=t.w;
    }

    // ---- hidden: h = relu(in @ W1 + b1), W1[80][16] (uniform -> s_load) ----
    float h[16];
#pragma unroll
    for (int k = 0; k < 16; ++k) h[k] = b1[k];
#pragma unroll
    for (int i = 0; i < 80; ++i)
#pragma unroll
        for (int k = 0; k < 16; ++k)
            h[k] = fmaf(in[i], W1[i*16 + k], h[k]);
#pragma unroll
    for (int k = 0; k < 16; ++k) h[k] = fmaxf(h[k], 0.0f);

    const int er = lane >> 4;   // 0..3
    const int jj = lane & 15;   // 0..15

    // ---- output in chunks of 16 feats: m = h @ W2 + b2, W2[16][64] ----
#pragma unroll
    for (int j0 = 0; j0 < 64; j0 += 16) {
        float m[16];
#pragma unroll
        for (int t = 0; t < 16; ++t) m[t] = b2[j0 + t];
#pragma unroll
        for (int k = 0; k < 16; ++k)
#pragma unroll
            for (int t = 0; t < 16; ++t)
                m[t] = fmaf(h[k], W2[k*64 + j0 + t], m[t]);

        // prior chunk's LDS reads must complete before overwrite
        wave_lds_fence();
#pragma unroll
        for (int t = 0; t < 16; ++t) mld[lane][t] = fkey(m[t]);
        // writes visible to all lanes of this wave
        wave_lds_fence();

        // coalesced atomics: 64 lanes cover 4 dst rows x 16 consecutive feats
        // per instruction; fire-and-forget (no drain until kernel end).
#pragma unroll
        for (int eg = 0; eg < 16; ++eg) {
            const int ee = (eg << 2) | er;
            atomicMax(&rkey[((size_t)dld[ee] << 6) + (unsigned)(j0 + jj)],
                      mld[ee][jj]);
        }
    }
}

// ---------------- node kernel: decode + update MLP ----------------
// NOTE: rkey and out alias (both d_out). No __restrict__ on them; all reads
// of this thread's row happen before its writes in program order.
__global__ __launch_bounds__(256) void node_kernel(
    const float* __restrict__ x, const unsigned* rkey,
    const float* __restrict__ W1, const float* __restrict__ b1,
    const float* __restrict__ W2, const float* __restrict__ b2,
    float* out)
{
    const int v = blockIdx.x * 256 + threadIdx.x;
    if (v >= N_NODES) return;

    float in[128];
    const float4* xp = reinterpret_cast<const float4*>(x) + (size_t)v * 16;
#pragma unroll
    for (int c = 0; c < 16; ++c) {
        float4 t = xp[c];
        in[4*c+0]=t.x; in[4*c+1]=t.y; in[4*c+2]=t.z; in[4*c+3]=t.w;
    }
    const uint4* rp = reinterpret_cast<const uint4*>(rkey) + (size_t)v * 16;
#pragma unroll
    for (int c = 0; c < 16; ++c) {
        uint4 t = rp[c];
        unsigned ks[4] = {t.x, t.y, t.z, t.w};
#pragma unroll
        for (int q = 0; q < 4; ++q) {
            unsigned k = ks[q];
            unsigned u = (k & 0x80000000u) ? (k ^ 0x80000000u) : ~k;
            float f = __uint_as_float(u);
            // -inf (no in-edges) or non-finite -> 0, matching jnp.where(isfinite)
            if (!(f >= -3.402823466e38f && f <= 3.402823466e38f)) f = 0.0f;
            in[64 + 4*c + q] = f;
        }
    }

    float h[16];
#pragma unroll
    for (int k = 0; k < 16; ++k) h[k] = b1[k];
#pragma unroll
    for (int i = 0; i < 128; ++i)
#pragma unroll
        for (int k = 0; k < 16; ++k)
            h[k] = fmaf(in[i], W1[i*16 + k], h[k]);
#pragma unroll
    for (int k = 0; k < 16; ++k) h[k] = fmaxf(h[k], 0.0f);

    float* op = out + (size_t)v * 64;
#pragma unroll
    for (int c = 0; c < 16; ++c) {
        float oo[4];
#pragma unroll
        for (int q = 0; q < 4; ++q) {
            float a = b2[4*c + q];
#pragma unroll
            for (int k = 0; k < 16; ++k)
                a = fmaf(h[k], W2[k*64 + 4*c + q], a);
            oo[q] = a;
        }
        float4 o; o.x=oo[0]; o.y=oo[1]; o.z=oo[2]; o.w=oo[3];
        reinterpret_cast<float4*>(op)[c] = o;
    }
}

extern "C" void kernel_launch(void* const* d_in, const int* in_sizes, int n_in,
                              void* d_out, int out_size, void* d_ws, size_t ws_size,
                              hipStream_t stream) {
    const float* x   = (const float*)d_in[0];
    const float* ef  = (const float*)d_in[1];
    const int*   src = (const int*)d_in[2];
    const int*   dst = (const int*)d_in[3];
    const float* mW1 = (const float*)d_in[4];
    const float* mb1 = (const float*)d_in[5];
    const float* mW2 = (const float*)d_in[6];
    const float* mb2 = (const float*)d_in[7];
    const float* uW1 = (const float*)d_in[8];
    const float* ub1 = (const float*)d_in[9];
    const float* uW2 = (const float*)d_in[10];
    const float* ub2 = (const float*)d_in[11];

    unsigned* rkey = (unsigned*)d_out;  // 50000*64 u32 = 12.8 MB, reuse d_out
    float*    out  = (float*)d_out;

    hipLaunchKernelGGL(init_kernel, dim3(3125), dim3(256), 0, stream, rkey);
    hipLaunchKernelGGL(edge_kernel, dim3(12500), dim3(64), 0, stream,
                       x, ef, src, dst, mW1, mb1, mW2, mb2, rkey);
    hipLaunchKernelGGL(node_kernel, dim3((N_NODES + 255) / 256), dim3(256), 0, stream,
                       x, rkey, uW1, ub1, uW2, ub2, out);
}